// Round 7
// baseline (311.905 us; speedup 1.0000x reference)
//
#include <hip/hip_runtime.h>
#include <cstdint>

#define B_ 16384
#define S_ 1024
#define L_ 256
#define K_ 4096
#define H_ 64
#define TAU1 0.35f
#define TAU2 0.006f
#define SLOTCAP 8192
#define SBIAS 1024.0f

typedef __attribute__((ext_vector_type(8))) short short8;
typedef __attribute__((ext_vector_type(4))) float floatx4;

#define AS1 __attribute__((address_space(1)))
#define AS3 __attribute__((address_space(3)))

__device__ __forceinline__ unsigned int f2ord(float f) {
  unsigned int u = __float_as_uint(f);
  return (u & 0x80000000u) ? ~u : (u | 0x80000000u);
}
__device__ __forceinline__ float ord2f(unsigned int o) {
  unsigned int u = (o & 0x80000000u) ? (o ^ 0x80000000u) : ~o;
  return __uint_as_float(u);
}
// round-to-nearest-even fp32 -> bf16
__device__ __forceinline__ unsigned short bf16rne(float f, float* hif) {
  unsigned int u = __float_as_uint(f);
  unsigned int r = (u + 0x7fffu + ((u >> 16) & 1u)) >> 16;
  *hif = __uint_as_float(r << 16);
  return (unsigned short)r;
}
__device__ __forceinline__ void bf16split(float f, unsigned short* hi, unsigned short* lo) {
  float hif, d;
  *hi = bf16rne(f, &hif);
  *lo = bf16rne(f - hif, &d);
}

__device__ __forceinline__ void fma16(const float4 a, const float4 b, float acc[4][4]) {
  const float av[4] = {a.x, a.y, a.z, a.w};
  const float bv[4] = {b.x, b.y, b.z, b.w};
#pragma unroll
  for (int ii = 0; ii < 4; ++ii)
#pragma unroll
    for (int jj = 0; jj < 4; ++jj)
      acc[ii][jj] = fmaf(av[ii], bv[jj], acc[ii][jj]);
}

// ---------------- K0a: wnorm[c] = ||emb[c]||^2 ----------------
__global__ __launch_bounds__(256)
void wnorm_kernel(const float* __restrict__ emb, float* __restrict__ wnorm) {
  const int lane = threadIdx.x & 63, wv = threadIdx.x >> 6;
  const int c = blockIdx.x * 4 + wv;
  const float4 v = *(const float4*)(emb + (long)c * L_ + (lane << 2));
  float s = v.x * v.x + v.y * v.y + v.z * v.z + v.w * v.w;
#pragma unroll
  for (int off = 32; off > 0; off >>= 1) s += __shfl_down(s, off, 64);
  if (lane == 0) wnorm[c] = s;
}

// ---------------- K0b: emb -> bf16 hi/lo ----------------
__global__ __launch_bounds__(256)
void cvt_emb_kernel(const float* __restrict__ emb, unsigned short* __restrict__ hi,
                    unsigned short* __restrict__ lo) {
  const size_t i = ((size_t)blockIdx.x * 256 + threadIdx.x) * 4;
  const float4 v = *(const float4*)(emb + i);
  ushort4 hv, lv;
  bf16split(v.x, &hv.x, &lv.x);
  bf16split(v.y, &hv.y, &lv.y);
  bf16split(v.z, &hv.z, &lv.z);
  bf16split(v.w, &hv.w, &lv.w);
  *(ushort4*)(hi + i) = hv;
  *(ushort4*)(lo + i) = lv;
}

// ---------------- K0c: transpose+split: dst[c][r] = src[r][c] (hi/lo bf16) ----------------
__global__ __launch_bounds__(256)
void tsplit_kernel(const float* __restrict__ src, int srows, int scols,
                   unsigned short* __restrict__ hi, unsigned short* __restrict__ lo) {
  __shared__ float tile[64][68];
  const int t = threadIdx.x;
  const int r0 = blockIdx.y * 64, c0 = blockIdx.x * 64;
  const int a = t & 63, q = t >> 6;
#pragma unroll
  for (int i = 0; i < 4; ++i) {
    const int cq = q * 16 + i * 4;
    *(float4*)&tile[a][cq] = *(const float4*)(src + (size_t)(r0 + a) * scols + c0 + cq);
  }
  __syncthreads();
  const int rx = t & 15, cy = t >> 4;
#pragma unroll
  for (int i = 0; i < 4; ++i) {
    const int cl = i * 16 + cy;
    float4 w;
    w.x = tile[rx * 4 + 0][cl];
    w.y = tile[rx * 4 + 1][cl];
    w.z = tile[rx * 4 + 2][cl];
    w.w = tile[rx * 4 + 3][cl];
    ushort4 hv, lv;
    bf16split(w.x, &hv.x, &lv.x);
    bf16split(w.y, &hv.y, &lv.y);
    bf16split(w.z, &hv.z, &lv.z);
    bf16split(w.w, &hv.w, &lv.w);
    *(ushort4*)(hi + (size_t)(c0 + cl) * srows + r0 + rx * 4) = hv;
    *(ushort4*)(lo + (size_t)(c0 + cl) * srows + r0 + rx * 4) = lv;
  }
}

// ---------------- K1: partial h chains: hp[by] = x[:, by-quarter] @ w1[by-quarter] ----
// grid (128, 4), 128 threads (2 waves). BM=128, BK=32, K-split x4 -> 512
// blocks = 2 blocks/CU (2 barrier domains). Thread tile 8x8: per k =
// 4 ds_read_b128 per 64 FMA-instr (ratio 16; R6's 8x4 was ratio 10.7) ->
// LDS-pipe bound 49K cyc/CU = 20.4 us (was 74K = 31). FMA floor 13.7 us.
// The per-CU LDS read count is FMA/ratio -- invariant to occupancy -- so
// geometry, not wave count, is the lever (R5/R6 lesson).
// Raw partials; enc2 combines: h = relu(((hp0+hp1)+hp2)+hp3 + b1).
// Same reorder class as R6's 2-split (passed, absmax unchanged).
// Banks: a-reads 2-way (free), b-reads 2-way + broadcast, writes 2-way.
__global__ __launch_bounds__(128)
void enc1_kernel(const float* __restrict__ x, const float* __restrict__ w1,
                 float* __restrict__ hp) {
  __shared__ float xs[2][32][128];  // [buf][k][row]
  __shared__ float ws[2][32][64];   // [buf][k][col]
  const int t = threadIdx.x;        // 0..127
  const int lane = t & 63, wv = t >> 6;
  const int tx = t & 7;             // col-group: cols tx*8..+8
  const int ty = t >> 3;            // row-group: rows ty*8..+8 (0..15)
  const long row0 = (long)blockIdx.x * 128;
  const int kbase = blockIdx.y * 256;

  float acc[8][8] = {};

#define ENC1_STAGE_W(buf, k0v)                                                     \
  do {                                                                             \
    const char* wsrc_ = (const char*)(w1 + (size_t)(k0v) * H_);                    \
    char* wdst_ = (char*)&ws[buf][0][0];                                           \
    _Pragma("unroll")                                                              \
    for (int is_ = 0; is_ < 4; ++is_)                                              \
      __builtin_amdgcn_global_load_lds(                                            \
          (const AS1 void*)(wsrc_ + (wv * 4 + is_) * 1024 + lane * 16),            \
          (AS3 void*)(wdst_ + (wv * 4 + is_) * 1024), 16, 0, 0);                   \
  } while (0)

  // prologue: stage step 0 (w via global_load_lds; x reg->transposed ds_write)
  ENC1_STAGE_W(0, kbase);
  {
    float4 cv[8];
#pragma unroll
    for (int j = 0; j < 8; ++j)
      cv[j] = *(const float4*)(x + (row0 + t) * S_ + kbase + 4 * j);
#pragma unroll
    for (int j = 0; j < 8; ++j)
#pragma unroll
      for (int jj = 0; jj < 4; ++jj)
        xs[0][4 * j + jj][t] = ((const float*)&cv[j])[jj];
  }
  __syncthreads();

  for (int s = 0; s < 8; ++s) {
    const int cur = s & 1;
    float4 nv[8];
    const bool pf = (s < 7);
    if (pf) {
      const int k0n = kbase + (s + 1) * 32;
      ENC1_STAGE_W(cur ^ 1, k0n);
#pragma unroll
      for (int j = 0; j < 8; ++j)
        nv[j] = *(const float4*)(x + (row0 + t) * S_ + k0n + 4 * j);
    }
#pragma unroll 4
    for (int k = 0; k < 32; ++k) {
      const float4 a0 = *(const float4*)&xs[cur][k][ty * 8];
      const float4 a1 = *(const float4*)&xs[cur][k][ty * 8 + 4];
      const float4 b0 = *(const float4*)&ws[cur][k][tx * 8];
      const float4 b1v = *(const float4*)&ws[cur][k][tx * 8 + 4];
      const float av[8] = {a0.x, a0.y, a0.z, a0.w, a1.x, a1.y, a1.z, a1.w};
      const float bv[8] = {b0.x, b0.y, b0.z, b0.w, b1v.x, b1v.y, b1v.z, b1v.w};
#pragma unroll
      for (int ii = 0; ii < 8; ++ii)
#pragma unroll
        for (int jj = 0; jj < 8; ++jj)
          acc[ii][jj] = fmaf(av[ii], bv[jj], acc[ii][jj]);
    }
    if (pf) {
#pragma unroll
      for (int j = 0; j < 8; ++j)
#pragma unroll
        for (int jj = 0; jj < 4; ++jj)
          xs[cur ^ 1][4 * j + jj][t] = ((const float*)&nv[j])[jj];
    }
    __syncthreads();
  }
#undef ENC1_STAGE_W

  float* hpo = hp + (size_t)blockIdx.y * B_ * H_;
#pragma unroll
  for (int ii = 0; ii < 8; ++ii) {
#pragma unroll
    for (int j2 = 0; j2 < 2; ++j2) {
      float4 o;
      o.x = acc[ii][j2 * 4 + 0];
      o.y = acc[ii][j2 * 4 + 1];
      o.z = acc[ii][j2 * 4 + 2];
      o.w = acc[ii][j2 * 4 + 3];
      *(float4*)(hpo + (row0 + ty * 8 + ii) * H_ + tx * 8 + j2 * 4) = o;
    }
  }
}

// ---------------- K2: e = h @ w2 + b2 (fp32 + bf16 hi/lo) ----------------
// grid (256, 2): column-split x2 -> 512 blocks = 2 blocks/CU. h combined
// during staging: h = relu(((hp0+hp1)+hp2)+hp3 + b1) (fixed order, bias
// last). hs [64][68] staged once per block; ws double-buffered via
// global_load_lds over this block's 2 column passes. 4x4 per thread.
__global__ __launch_bounds__(256)
void enc2_kernel(const float* __restrict__ hp, const float* __restrict__ w2,
                 const float* __restrict__ b1, const float* __restrict__ b2,
                 float* __restrict__ e32,
                 unsigned short* __restrict__ e_hi, unsigned short* __restrict__ e_lo) {
  __shared__ float hs[64][68];      // [k][row(+pad)]
  __shared__ float ws[2][64][64];   // [buf][k][col]
  const int t = threadIdx.x;
  const int lane = t & 63, wv = t >> 6;
  const int tx = t & 15, ty = t >> 4;
  const long row0 = (long)blockIdx.x * 64;
  const int p0 = blockIdx.y * 2;    // this block's 2 column passes

#define ENC2_STAGE_W(buf, c0v)                                                     \
  do {                                                                             \
    char* wdst_ = (char*)&ws[buf][0][0];                                           \
    _Pragma("unroll")                                                              \
    for (int is_ = 0; is_ < 4; ++is_) {                                            \
      const int krow_ = wv * 16 + is_ * 4 + (lane >> 4);                           \
      const float* src_ = w2 + (size_t)krow_ * L_ + (c0v) + (lane & 15) * 4;       \
      __builtin_amdgcn_global_load_lds((const AS1 void*)src_,                      \
          (AS3 void*)(wdst_ + (wv * 16 + is_ * 4) * 256), 16, 0, 0);               \
    }                                                                              \
  } while (0)

  // prologue: stage h tile (combine 4 partials + bias + relu, transposed)
  ENC2_STAGE_W(0, p0 * 64);
  {
    const int srow = t >> 2;
    const int kq4 = (t & 3) * 16;
    const float* h0 = hp;
    const float* h1 = hp + (size_t)B_ * H_;
    const float* h2 = hp + (size_t)2 * B_ * H_;
    const float* h3 = hp + (size_t)3 * B_ * H_;
    float4 cv[4];
#pragma unroll
    for (int j = 0; j < 4; ++j) {
      const size_t off = (size_t)(row0 + srow) * H_ + kq4 + 4 * j;
      const float4 va = *(const float4*)(h0 + off);
      const float4 vb = *(const float4*)(h1 + off);
      const float4 vc = *(const float4*)(h2 + off);
      const float4 vd = *(const float4*)(h3 + off);
      const float4 bb = *(const float4*)(b1 + kq4 + 4 * j);
      cv[j].x = fmaxf(((va.x + vb.x) + vc.x) + vd.x + bb.x, 0.f);
      cv[j].y = fmaxf(((va.y + vb.y) + vc.y) + vd.y + bb.y, 0.f);
      cv[j].z = fmaxf(((va.z + vb.z) + vc.z) + vd.z + bb.z, 0.f);
      cv[j].w = fmaxf(((va.w + vb.w) + vc.w) + vd.w + bb.w, 0.f);
    }
#pragma unroll
    for (int j = 0; j < 4; ++j)
#pragma unroll
      for (int jj = 0; jj < 4; ++jj)
        hs[kq4 + 4 * j + jj][srow] = ((const float*)&cv[j])[jj];
  }
  __syncthreads();

  for (int pi = 0; pi < 2; ++pi) {
    const int cur = pi & 1;
    const int c0 = (p0 + pi) * 64;
    if (pi < 1) ENC2_STAGE_W(cur ^ 1, c0 + 64);
    float acc[4][4] = {};
#pragma unroll 8
    for (int k = 0; k < 64; ++k) {
      const float4 a = *(const float4*)&hs[k][ty * 4];
      const float4 b = *(const float4*)&ws[cur][k][tx * 4];
      fma16(a, b, acc);
    }
    const float4 bb = *(const float4*)(b2 + c0 + tx * 4);
#pragma unroll
    for (int ii = 0; ii < 4; ++ii) {
      const long row = row0 + ty * 4 + ii;
      float4 o;
      o.x = acc[ii][0] + bb.x;
      o.y = acc[ii][1] + bb.y;
      o.z = acc[ii][2] + bb.z;
      o.w = acc[ii][3] + bb.w;
      *(float4*)(e32 + row * L_ + c0 + tx * 4) = o;
      ushort4 hv, lv;
      bf16split(o.x, &hv.x, &lv.x);
      bf16split(o.y, &hv.y, &lv.y);
      bf16split(o.z, &hv.z, &lv.z);
      bf16split(o.w, &hv.w, &lv.w);
      *(ushort4*)(e_hi + row * L_ + c0 + tx * 4) = hv;
      *(ushort4*)(e_lo + row * L_ + c0 + tx * 4) = lv;
    }
    __syncthreads();
  }
#undef ENC2_STAGE_W
}

// ---------------- K3: pass-1 hi*hi distance + per-row top-2 ----------------
// grid (B_/128, 8). 128 rows x 512 codes per block. Double-buffered staging,
// one barrier per step. 32-bit biased-score keys, branchless top-2.
// launch_bounds (256,3): cap ~170 VGPR+AGPR -> no spill (R1's (256,4) cap=128
// spilled acc -> 59 MB scratch writes/dispatch).
__global__ __launch_bounds__(256, 3)
void dist_hi_kernel(const unsigned short* __restrict__ emb_hi,
                    const unsigned short* __restrict__ e_hi,
                    const float* __restrict__ wnorm, uint4* __restrict__ part) {
  __shared__ char smem[32768];        // [buf][sA 8K | sB 8K]
  __shared__ float wnormb_s[512];
  const int t = threadIdx.x;
  const int lane = t & 63, wv = t >> 6;
  const int wm = wv >> 1, wn = wv & 1;
  const int n0 = blockIdx.x * 128;
  const int cbase = blockIdx.y * 512;

  const int lr = lane >> 2;
  const int sst = (lr + (lane >> 4)) & 3;
  const int qsrc = ((lane & 3) - sst) & 3;
  const size_t lane_goff = (size_t)lr * (L_ * 2) + (size_t)qsrc * 16;

  const int ln = lane & 15, quad = lane >> 4;
  const int sfr = (ln + (ln >> 2)) & 3;
  const int qp = (quad + sfr) & 3;

  const bool isA = (wv < 2);
  const size_t rowHalfOff = (size_t)((wv & 1) * 64) * (L_ * 2);
  const char* gA = (const char*)emb_hi + (size_t)cbase * (L_ * 2) + rowHalfOff + lane_goff;
  const char* gB = (const char*)e_hi + (size_t)n0 * (L_ * 2) + rowHalfOff + lane_goff;
  char* const dstBase = smem + (isA ? 0 : 8192) + (wv & 1) * 4096;

  // prologue: stage (mt=0,kc=0) into buf0; preload biased wnorm
  {
    const char* src = isA ? gA : gB;
#pragma unroll
    for (int is = 0; is < 4; ++is)
      __builtin_amdgcn_global_load_lds((const AS1 void*)(src + (size_t)is * (16 * L_ * 2)),
                                       (AS3 void*)(dstBase + is * 1024), 16, 0, 0);
  }
  wnormb_s[t] = wnorm[cbase + t] + SBIAS;
  wnormb_s[t + 256] = wnorm[cbase + t + 256] + SBIAS;

  unsigned int k1[4], i1[4], k2[4];
#pragma unroll
  for (int nf = 0; nf < 4; ++nf) { k1[nf] = 0xffffffffu; k2[nf] = 0xffffffffu; i1[nf] = 0u; }

  floatx4 acc[4][4];
#pragma unroll
  for (int a = 0; a < 4; ++a)
#pragma unroll
    for (int b = 0; b < 4; ++b) acc[a][b] = (floatx4){0.f, 0.f, 0.f, 0.f};

  __syncthreads();  // buf0 staged (vmcnt drained by compiler), wnormb_s ready

  for (int mt = 0; mt < 4; ++mt) {
#pragma unroll
    for (int kc = 0; kc < 8; ++kc) {
      // prefetch step s+1 into the other buffer (skip only at very last step)
      if (mt < 3 || kc < 7) {
        const int nmt = (kc == 7) ? mt + 1 : mt;
        const int nkc = (kc + 1) & 7;
        char* dst = dstBase + ((kc + 1) & 1) * 16384;
        const char* src = isA ? (gA + (size_t)nmt * (128 * L_ * 2) + nkc * 64)
                              : (gB + nkc * 64);
#pragma unroll
        for (int is = 0; is < 4; ++is)
          __builtin_amdgcn_global_load_lds((const AS1 void*)(src + (size_t)is * (16 * L_ * 2)),
                                           (AS3 void*)(dst + is * 1024), 16, 0, 0);
      }
      const char* sAc = smem + (kc & 1) * 16384;
      const char* sBc = sAc + 8192;
      short8 ahi[4];
#pragma unroll
      for (int mf = 0; mf < 4; ++mf)
        ahi[mf] = *(const short8*)(sAc + (wm * 64 + mf * 16 + ln) * 64 + qp * 16);
#pragma unroll
      for (int nf = 0; nf < 4; ++nf) {
        const short8 bh = *(const short8*)(sBc + (wn * 64 + nf * 16 + ln) * 64 + qp * 16);
#pragma unroll
        for (int mf = 0; mf < 4; ++mf)
          acc[mf][nf] = __builtin_amdgcn_mfma_f32_16x16x32_bf16(ahi[mf], bh, acc[mf][nf], 0, 0, 0);
      }
      if (kc == 7) {
        // epilogue for this mt tile (overlaps with next tile's staging)
        const int mb = mt * 128 + wm * 64 + quad * 4;
        const unsigned int gb = (unsigned int)(cbase + mb);
#pragma unroll
        for (int mf = 0; mf < 4; ++mf) {
          const float4 w4 = *(const float4*)&wnormb_s[mb + mf * 16];
          const float* wp = (const float*)&w4;
#pragma unroll
          for (int nf = 0; nf < 4; ++nf) {
#pragma unroll
            for (int rr = 0; rr < 4; ++rr) {
              const float score = fmaf(-2.f, acc[mf][nf][rr], wp[rr]);
              const unsigned int k = __float_as_uint(score);
              const unsigned int id = gb + (unsigned int)(mf * 16 + rr);
              const bool lt1 = k < k1[nf];
              const bool lt2 = k < k2[nf];
              k2[nf] = lt1 ? k1[nf] : (lt2 ? k : k2[nf]);
              k1[nf] = lt1 ? k : k1[nf];
              i1[nf] = lt1 ? id : i1[nf];
              acc[mf][nf][rr] = 0.f;
            }
          }
        }
      }
      __syncthreads();
    }
  }
  // reduce across quads (lane bits 4,5)
#pragma unroll
  for (int d = 16; d <= 32; d <<= 1) {
#pragma unroll
    for (int nf = 0; nf < 4; ++nf) {
      const unsigned int ok1 = __shfl_xor(k1[nf], d, 64);
      const unsigned int oi1 = __shfl_xor(i1[nf], d, 64);
      const unsigned int ok2 = __shfl_xor(k2[nf], d, 64);
      const bool c = ok1 < k1[nf];
      const unsigned int hk = c ? k1[nf] : ok1;
      k1[nf] = c ? ok1 : k1[nf];
      i1[nf] = c ? oi1 : i1[nf];
      const unsigned int mk = ok2 < k2[nf] ? ok2 : k2[nf];
      k2[nf] = hk < mk ? hk : mk;
    }
  }
  if (lane < 16) {
    const int slice = blockIdx.y * 2 + wm;
#pragma unroll
    for (int nf = 0; nf < 4; ++nf) {
      const int row = n0 + wn * 64 + nf * 16 + lane;
      uint4 v;
      v.x = k1[nf]; v.y = i1[nf]; v.z = k2[nf]; v.w = 0u;
      part[(size_t)slice * B_ + row] = v;
    }
  }
}

// ---------------- K4: merge pass-1 partials, flag coarse-gap rows ----------------
__global__ __launch_bounds__(256)
void finalize1_kernel(const uint4* __restrict__ part, int* __restrict__ idx,
                      int* __restrict__ flagged, int* __restrict__ counter) {
  const int row = blockIdx.x * 256 + threadIdx.x;
  unsigned int k1 = 0xffffffffu, i1 = 0u, k2 = 0xffffffffu;
#pragma unroll
  for (int s = 0; s < 16; ++s) {
    const uint4 v = part[(size_t)s * B_ + row];
    const bool c = v.x < k1;
    const unsigned int hk = c ? k1 : v.x;
    k1 = c ? v.x : k1;
    i1 = c ? v.y : i1;
    const unsigned int mk = v.z < k2 ? v.z : k2;
    k2 = hk < mk ? hk : mk;
  }
  idx[row] = (int)i1;
  const float gap = __uint_as_float(k2) - __uint_as_float(k1);
  if (gap < TAU1) {
    const int p = atomicAdd(counter, 1);
    flagged[p] = row;
  }
}

// ---------------- K5: pass-2 3-term split-bf16 on flagged rows ----------------
// grid (16 rowgroup-stride, 16 slices of 256 codes); gathered e rows.
// Same pipeline treatment as dist_hi: double-buffered LDS (2x32K), flattened
// (mt,kc) steps with prefetch-before-compute, one barrier/step, 32-bit keys.
__global__ __launch_bounds__(256)
void dist3_kernel(const unsigned short* __restrict__ emb_hi, const unsigned short* __restrict__ emb_lo,
                  const unsigned short* __restrict__ e_hi, const unsigned short* __restrict__ e_lo,
                  const float* __restrict__ wnorm, const int* __restrict__ counter,
                  const int* __restrict__ flagged, uint4* __restrict__ part2) {
  __shared__ char smem[2][4 * 8192];   // [buf][Ahi|Alo|Bhi|Blo]
  __shared__ float wnormb_s[256];
  __shared__ int frow_s[128];
  const int t = threadIdx.x;
  const int lane = t & 63, wv = t >> 6;
  const int wm = wv >> 1, wn = wv & 1;
  const int slice = blockIdx.y;
  const int n = min(*counter, SLOTCAP);

  const int lr = lane >> 2;
  const int sst = (lr + (lane >> 4)) & 3;
  const int qsrc = ((lane & 3) - sst) & 3;
  const int ln = lane & 15, quad = lane >> 4;
  const int sfr = (ln + (ln >> 2)) & 3;
  const int qp = (quad + sfr) & 3;

  const bool isA = (wv < 2);
  const unsigned short* aBase = (wv & 1) ? emb_lo : emb_hi;
  const unsigned short* bBase = (wv & 1) ? e_lo : e_hi;

  wnormb_s[t] = wnorm[slice * 256 + t] + SBIAS;

  floatx4 acc[4][4];
#pragma unroll
  for (int a = 0; a < 4; ++a)
#pragma unroll
    for (int b = 0; b < 4; ++b) acc[a][b] = (floatx4){0.f, 0.f, 0.f, 0.f};

#define STAGE3(bufidx, m0v, kcv)                                                        \
  do {                                                                                  \
    char* dst_ = smem[bufidx] + wv * 8192;                                              \
    _Pragma("unroll")                                                                   \
    for (int is_ = 0; is_ < 8; ++is_) {                                                 \
      const int row_ = is_ * 16 + lr;                                                   \
      const char* src_ = isA ? (const char*)(aBase + (size_t)((m0v) + row_) * L_)       \
                             : (const char*)(bBase + (size_t)frow_s[row_] * L_);        \
      src_ += (kcv) * 64 + qsrc * 16;                                                   \
      __builtin_amdgcn_global_load_lds((const AS1 void*)src_,                           \
                                       (AS3 void*)(dst_ + is_ * 1024), 16, 0, 0);       \
    }                                                                                   \
  } while (0)

  for (int gi = blockIdx.x; gi * 128 < n; gi += 16) {
    const int s0 = gi * 128;
    __syncthreads();                       // prev gi fully done with LDS
    if (t < 128) frow_s[t] = flagged[min(s0 + t, n - 1)];
    __syncthreads();                       // frow_s ready (and wnormb_s on first gi)
    STAGE3(0, slice * 256, 0);             // stage step 0 (mt=0, kc=0)

    unsigned int k1[4], i1[4], k2[4];
#pragma unroll
    for (int nf = 0; nf < 4; ++nf) { k1[nf] = 0xffffffffu; k2[nf] = 0xffffffffu; i1[nf] = 0u; }

    __syncthreads();                       // buf0 staged (vmcnt drained)

    for (int s = 0; s < 16; ++s) {
      const int mt = s >> 3, kc = s & 7;
      if (s < 15) {
        const int ns = s + 1;
        STAGE3(ns & 1, slice * 256 + (ns >> 3) * 128, ns & 7);
      }
      const char* base = smem[s & 1];
      const char* sAhi = base;
      const char* sAlo = base + 8192;
      const char* sBhi = base + 16384;
      const char* sBlo = base + 24576;
      short8 ahi[4], alo[4];
#pragma unroll
      for (int mf = 0; mf < 4; ++mf) {
        const int rb = (mf * 16 + wm * 64 + ln) * 64 + qp * 16;
        ahi[mf] = *(const short8*)(sAhi + rb);
        alo[mf] = *(const short8*)(sAlo + rb);
      }
#pragma unroll
      for (int nf = 0; nf < 4; ++nf) {
        const int rb = (nf * 16 + wn * 64 + ln) * 64 + qp * 16;
        const short8 bhi = *(const short8*)(sBhi + rb);
        const short8 blo = *(const short8*)(sBlo + rb);
#pragma unroll
        for (int mf = 0; mf < 4; ++mf) {
          acc[mf][nf] = __builtin_amdgcn_mfma_f32_16x16x32_bf16(ahi[mf], bhi, acc[mf][nf], 0, 0, 0);
          acc[mf][nf] = __builtin_amdgcn_mfma_f32_16x16x32_bf16(ahi[mf], blo, acc[mf][nf], 0, 0, 0);
          acc[mf][nf] = __builtin_amdgcn_mfma_f32_16x16x32_bf16(alo[mf], bhi, acc[mf][nf], 0, 0, 0);
        }
      }
      if (kc == 7) {
        const int mb = mt * 128 + wm * 64 + quad * 4;
        const unsigned int gb = (unsigned int)(slice * 256 + mb);
#pragma unroll
        for (int mf = 0; mf < 4; ++mf) {
          const float4 w4 = *(const float4*)&wnormb_s[mb + mf * 16];
          const float* wp = (const float*)&w4;
#pragma unroll
          for (int nf = 0; nf < 4; ++nf) {
#pragma unroll
            for (int rr = 0; rr < 4; ++rr) {
              const float score = fmaf(-2.f, acc[mf][nf][rr], wp[rr]);
              const unsigned int k = __float_as_uint(score);
              const unsigned int id = gb + (unsigned int)(mf * 16 + rr);
              const bool lt1 = k < k1[nf];
              const bool lt2 = k < k2[nf];
              k2[nf] = lt1 ? k1[nf] : (lt2 ? k : k2[nf]);
              k1[nf] = lt1 ? k : k1[nf];
              i1[nf] = lt1 ? id : i1[nf];
              acc[mf][nf][rr] = 0.f;
            }
          }
        }
      }
      __syncthreads();
    }
    // reduce across quads (lane bits 4,5)
#pragma unroll
    for (int d = 16; d <= 32; d <<= 1) {
#pragma unroll
      for (int nf = 0; nf < 4; ++nf) {
        const unsigned int ok1 = __shfl_xor(k1[nf], d, 64);
        const unsigned int oi1 = __shfl_xor(i1[nf], d, 64);
        const unsigned int ok2 = __shfl_xor(k2[nf], d, 64);
        const bool c = ok1 < k1[nf];
        const unsigned int hk = c ? k1[nf] : ok1;
        k1[nf] = c ? ok1 : k1[nf];
        i1[nf] = c ? oi1 : i1[nf];
        const unsigned int mk = ok2 < k2[nf] ? ok2 : k2[nf];
        k2[nf] = hk < mk ? hk : mk;
      }
    }
    if (lane < 16) {
      const int sub = slice * 2 + wm;   // 32 sub-slices
#pragma unroll
      for (int nf = 0; nf < 4; ++nf) {
        const int slot = s0 + wn * 64 + nf * 16 + lane;
        if (slot < n) {
          uint4 v;
          v.x = k1[nf]; v.y = i1[nf]; v.z = k2[nf]; v.w = 0u;
          part2[(size_t)sub * SLOTCAP + slot] = v;
        }
      }
    }
  }
#undef STAGE3
}

// ---------------- K6: merge pass-2 partials, flag fine-gap rows ----------------
__global__ __launch_bounds__(256)
void finalize2_kernel(const uint4* __restrict__ part2, const int* __restrict__ counter,
                      const int* __restrict__ flagged, int* __restrict__ idx,
                      int* __restrict__ flagged2, int* __restrict__ counter2) {
  const int n = min(*counter, SLOTCAP);
  const int s = blockIdx.x * 256 + threadIdx.x;
  if (s >= n) return;
  unsigned int k1 = 0xffffffffu, i1 = 0u, k2 = 0xffffffffu;
#pragma unroll
  for (int sub = 0; sub < 32; ++sub) {
    const uint4 v = part2[(size_t)sub * SLOTCAP + s];
    const bool c = v.x < k1;
    const unsigned int hk = c ? k1 : v.x;
    k1 = c ? v.x : k1;
    i1 = c ? v.y : i1;
    const unsigned int mk = v.z < k2 ? v.z : k2;
    k2 = hk < mk ? hk : mk;
  }
  const int row = flagged[s];
  idx[row] = (int)i1;
  if (__uint_as_float(k2) - __uint_as_float(k1) < TAU2) {
    const int p = atomicAdd(counter2, 1);
    flagged2[p] = row;
  }
}

// ---------------- K7: exact fp32 recheck (parallel over code chunks) ----------------
// grid (16 code-chunks, 16 row-slots)
__global__ __launch_bounds__(256)
void recheck_kernel(const int* __restrict__ counter2, const int* __restrict__ flagged2,
                    const float* __restrict__ e32, const float* __restrict__ emb,
                    const float* __restrict__ wnorm, unsigned long long* __restrict__ keys2) {
  __shared__ float er[L_];
  const int t = threadIdx.x;
  const int lane = t & 63;
  const int n2 = *counter2;
  for (int i = blockIdx.y; i < n2; i += 16) {
    const int row = flagged2[i];
    __syncthreads();
    er[t] = e32[(size_t)row * L_ + t];
    __syncthreads();
    const int c = blockIdx.x * 256 + t;
    const float4* wr = (const float4*)(emb + (size_t)c * L_);
    float dot = 0.f;
#pragma unroll 16
    for (int l = 0; l < 64; ++l) {
      const float4 w = wr[l];
      dot = fmaf(w.x, er[4 * l + 0], dot);
      dot = fmaf(w.y, er[4 * l + 1], dot);
      dot = fmaf(w.z, er[4 * l + 2], dot);
      dot = fmaf(w.w, er[4 * l + 3], dot);
    }
    const float score = fmaf(-2.f, dot, wnorm[c]);
    unsigned long long key = ((unsigned long long)f2ord(score) << 32) | (unsigned int)c;
#pragma unroll
    for (int off = 32; off > 0; off >>= 1) {
      const unsigned long long o = __shfl_down(key, off, 64);
      key = o < key ? o : key;
    }
    if (lane == 0) atomicMin(&keys2[row], key);
  }
}

// ---------------- K8: write rechecked indices ----------------
__global__ __launch_bounds__(256)
void extract_kernel(const int* __restrict__ counter2, const int* __restrict__ flagged2,
                    const unsigned long long* __restrict__ keys2, int* __restrict__ idx) {
  const int n2 = *counter2;
  for (int i = threadIdx.x; i < n2; i += 256) {
    const int r = flagged2[i];
    idx[r] = (int)(keys2[r] & 0xffffffffull);
  }
}

// ---------------- K9: decoder, split-bf16 MFMA ----------------
// grid (B_/64, 2): blockIdx.y splits the output-S range (nc 0..3 vs 4..7).
__global__ __launch_bounds__(256)
void dec_mfma_kernel(const int* __restrict__ idx,
                     const unsigned short* __restrict__ emb_hi, const unsigned short* __restrict__ emb_lo,
                     const unsigned short* __restrict__ w1t_hi, const unsigned short* __restrict__ w1t_lo,
                     const unsigned short* __restrict__ w2t_hi, const unsigned short* __restrict__ w2t_lo,
                     const float* __restrict__ b1, const float* __restrict__ b2,
                     float* __restrict__ out) {
  __shared__ char stage[32768];
  __shared__ __align__(16) unsigned short g_hi[64][72];
  __shared__ __align__(16) unsigned short g_lo[64][72];
  __shared__ int idxs[64];
  const int t = threadIdx.x;
  const int lane = t & 63, wv = t >> 6;
  const long row0 = (long)blockIdx.x * 64;
  const int nc0 = blockIdx.y * 4;

  const int lr = lane >> 2;
  const int sst = (lr + (lane >> 4)) & 3;
  const int qsrc = ((lane & 3) - sst) & 3;
  const int ln = lane & 15, quad = lane >> 4;
  const int sfr = (ln + (ln >> 2)) & 3;
  const int qp = (quad + sfr) & 3;

  if (t < 64) idxs[t] = idx[row0 + t];
  __syncthreads();

  floatx4 acc1[4];
#pragma unroll
  for (int nf = 0; nf < 4; ++nf) acc1[nf] = (floatx4){0.f, 0.f, 0.f, 0.f};

  for (int kc = 0; kc < 8; ++kc) {
    char* dst = stage + wv * 4096;
#pragma unroll
    for (int is = 0; is < 4; ++is) {
      const int row = is * 16 + lr;
      const char* src;
      if (wv == 0)      src = (const char*)(emb_hi + (size_t)idxs[row] * L_) + kc * 64 + qsrc * 16;
      else if (wv == 1) src = (const char*)(emb_lo + (size_t)idxs[row] * L_) + kc * 64 + qsrc * 16;
      else if (wv == 2) src = (const char*)(w1t_hi + (size_t)row * L_) + kc * 64 + qsrc * 16;
      else              src = (const char*)(w1t_lo + (size_t)row * L_) + kc * 64 + qsrc * 16;
      __builtin_amdgcn_global_load_lds((const AS1 void*)src, (AS3 void*)(dst + is * 1024), 16, 0, 0);
    }
    __syncthreads();
    const int arb = (16 * wv + ln) * 64 + qp * 16;
    const short8 ahi = *(const short8*)(stage + arb);
    const short8 alo = *(const short8*)(stage + 4096 + arb);
#pragma unroll
    for (int nf = 0; nf < 4; ++nf) {
      const int brb = (nf * 16 + ln) * 64 + qp * 16;
      const short8 bhi = *(const short8*)(stage + 8192 + brb);
      const short8 blo = *(const short8*)(stage + 12288 + brb);
      acc1[nf] = __builtin_amdgcn_mfma_f32_16x16x32_bf16(ahi, bhi, acc1[nf], 0, 0, 0);
      acc1[nf] = __builtin_amdgcn_mfma_f32_16x16x32_bf16(ahi, blo, acc1[nf], 0, 0, 0);
      acc1[nf] = __builtin_amdgcn_mfma_f32_16x16x32_bf16(alo, bhi, acc1[nf], 0, 0, 0);
    }
    __syncthreads();
  }
#pragma unroll
  for (int nf = 0; nf < 4; ++nf) {
    const int col = nf * 16 + ln;
    const float bias = b1[col];
#pragma unroll
    for (int rr = 0; rr < 4; ++rr) {
      const int row = 16 * wv + quad * 4 + rr;
      const float gv = fmaxf(acc1[nf][rr] + bias, 0.f);
      unsigned short hv, lv;
      bf16split(gv, &hv, &lv);
      g_hi[row][col] = hv;
      g_lo[row][col] = lv;
    }
  }
  __syncthreads();

  for (int nc = nc0; nc < nc0 + 4; ++nc) {
    char* dst = stage + wv * 8192;
    const unsigned short* base = (wv < 2) ? w2t_hi : w2t_lo;
    const int kh = wv & 1;
#pragma unroll
    for (int is = 0; is < 8; ++is) {
      const int row = is * 16 + lr;
      const char* src = (const char*)(base + (size_t)(nc * 128 + row) * H_) + kh * 64 + qsrc * 16;
      __builtin_amdgcn_global_load_lds((const AS1 void*)src, (AS3 void*)(dst + is * 1024), 16, 0, 0);
    }
    __syncthreads();
    floatx4 acc2[8];
#pragma unroll
    for (int nf = 0; nf < 8; ++nf) acc2[nf] = (floatx4){0.f, 0.f, 0.f, 0.f};
#pragma unroll
    for (int ks = 0; ks < 2; ++ks) {
      const int ab = (16 * wv + ln) * 144 + ks * 64 + quad * 16;
      const short8 ahi = *(const short8*)((const char*)g_hi + ab);
      const short8 alo = *(const short8*)((const char*)g_lo + ab);
#pragma unroll
      for (int nf = 0; nf < 8; ++nf) {
        const int brb = (nf * 16 + ln) * 64 + qp * 16;
        const short8 bhi = *(const short8*)(stage + ks * 8192 + brb);
        const short8 blo = *(const short8*)(stage + (2 + ks) * 8192 + brb);
        acc2[nf] = __builtin_amdgcn_mfma_f32_16x16x32_bf16(ahi, bhi, acc2[nf], 0, 0, 0);
        acc2[nf] = __builtin_amdgcn_mfma_f32_16x16x32_bf16(ahi, blo, acc2[nf], 0, 0, 0);
        acc2[nf] = __builtin_amdgcn_mfma_f32_16x16x32_bf16(alo, bhi, acc2[nf], 0, 0, 0);
      }
    }
    __syncthreads();
#pragma unroll
    for (int nf = 0; nf < 8; ++nf) {
      const int s = nc * 128 + nf * 16 + ln;
      const float bias = b2[s];
#pragma unroll
      for (int rr = 0; rr < 4; ++rr) {
        const long row = row0 + 16 * wv + quad * 4 + rr;
        out[row * S_ + s] = acc2[nf][rr] + bias;
      }
    }
  }
}

extern "C" void kernel_launch(void* const* d_in, const int* in_sizes, int n_in,
                              void* d_out, int out_size, void* d_ws, size_t ws_size,
                              hipStream_t stream) {
  (void)in_sizes; (void)n_in; (void)out_size; (void)ws_size;
  const float* x      = (const float*)d_in[0];
  const float* enc_w1 = (const float*)d_in[1];
  const float* enc_b1 = (const float*)d_in[2];
  const float* enc_w2 = (const float*)d_in[3];
  const float* enc_b2 = (const float*)d_in[4];
  const float* emb    = (const float*)d_in[5];
  const float* dec_w1 = (const float*)d_in[6];
  const float* dec_b1 = (const float*)d_in[7];
  const float* dec_w2 = (const float*)d_in[8];
  const float* dec_b2 = (const float*)d_in[9];
  float* out = (float*)d_out;

  char* p = (char*)d_ws;
  float* hp   = (float*)p;          p += (size_t)4 * B_ * H_ * 4; // 16 MB (4 k-quarters)
  // hp is dead after enc2; part/part2 alias into it (stream order serializes)
  uint4* part  = (uint4*)hp;                                      // 4 MB (dist_hi)
  uint4* part2 = (uint4*)((char*)hp + (size_t)16 * B_ * 16);      // 4 MB (dist3)
  float* e32  = (float*)p;          p += (size_t)B_ * L_ * 4;   // 16 MB
  unsigned short* e_hi = (unsigned short*)p;   p += (size_t)B_ * L_ * 2;  // 8 MB
  unsigned short* e_lo = (unsigned short*)p;   p += (size_t)B_ * L_ * 2;  // 8 MB
  unsigned short* emb_hi = (unsigned short*)p; p += (size_t)K_ * L_ * 2;  // 2 MB
  unsigned short* emb_lo = (unsigned short*)p; p += (size_t)K_ * L_ * 2;  // 2 MB
  unsigned short* w1t_hi = (unsigned short*)p; p += (size_t)H_ * L_ * 2;  // 32 KB
  unsigned short* w1t_lo = (unsigned short*)p; p += (size_t)H_ * L_ * 2;  // 32 KB
  unsigned short* w2t_hi = (unsigned short*)p; p += (size_t)S_ * H_ * 2;  // 128 KB
  unsigned short* w2t_lo = (unsigned short*)p; p += (size_t)S_ * H_ * 2;  // 128 KB
  float* wnrm = (float*)p;          p += (size_t)K_ * 4;        // 16 KB
  unsigned long long* keys2 = (unsigned long long*)p; p += (size_t)B_ * 8; // 128 KB
  int* idx      = (int*)p;          p += (size_t)B_ * 4;        // 64 KB
  int* flagged  = (int*)p;          p += (size_t)B_ * 4;        // 64 KB
  int* flagged2 = (int*)p;          p += (size_t)B_ * 4;        // 64 KB
  int* counters = (int*)p;          p += 256;                   // [0]=n flagged, [1]=n2

  hipMemsetAsync(counters, 0, 8, stream);
  hipMemsetAsync(keys2, 0xFF, (size_t)B_ * 8, stream);
  wnorm_kernel<<<K_ / 4, 256, 0, stream>>>(emb, wnrm);
  cvt_emb_kernel<<<(K_ * L_) / 1024, 256, 0, stream>>>(emb, emb_hi, emb_lo);
  tsplit_kernel<<<dim3(1, 4), 256, 0, stream>>>(dec_w1, L_, H_, w1t_hi, w1t_lo);
  tsplit_kernel<<<dim3(16, 1), 256, 0, stream>>>(dec_w2, H_, S_, w2t_hi, w2t_lo);
  enc1_kernel<<<dim3(B_ / 128, 4), 128, 0, stream>>>(x, enc_w1, hp);
  enc2_kernel<<<dim3(B_ / 64, 2), 256, 0, stream>>>(hp, enc_w2, enc_b1, enc_b2,
                                                    e32, e_hi, e_lo);
  dist_hi_kernel<<<dim3(B_ / 128, 8), 256, 0, stream>>>(emb_hi, e_hi, wnrm, part);
  finalize1_kernel<<<B_ / 256, 256, 0, stream>>>(part, idx, flagged, counters);
  dist3_kernel<<<dim3(16, 16), 256, 0, stream>>>(emb_hi, emb_lo, e_hi, e_lo, wnrm,
                                                 counters, flagged, part2);
  finalize2_kernel<<<SLOTCAP / 256, 256, 0, stream>>>(part2, counters, flagged, idx,
                                                      flagged2, counters + 1);
  recheck_kernel<<<dim3(16, 16), 256, 0, stream>>>(counters + 1, flagged2, e32, emb, wnrm, keys2);
  extract_kernel<<<1, 256, 0, stream>>>(counters + 1, flagged2, keys2, idx);
  dec_mfma_kernel<<<dim3(B_ / 64, 2), 256, 0, stream>>>(idx, emb_hi, emb_lo, w1t_hi, w1t_lo,
                                                        w2t_hi, w2t_lo, dec_b1, dec_b2, out);
}

// Round 8
// 301.285 us; speedup vs baseline: 1.0352x; 1.0352x over previous
//
#include <hip/hip_runtime.h>
#include <cstdint>

#define B_ 16384
#define S_ 1024
#define L_ 256
#define K_ 4096
#define H_ 64
#define TAU1 0.35f
#define TAU2 0.006f
#define SLOTCAP 8192
#define SBIAS 1024.0f

typedef __attribute__((ext_vector_type(8))) short short8;
typedef __attribute__((ext_vector_type(4))) float floatx4;

#define AS1 __attribute__((address_space(1)))
#define AS3 __attribute__((address_space(3)))

__device__ __forceinline__ unsigned int f2ord(float f) {
  unsigned int u = __float_as_uint(f);
  return (u & 0x80000000u) ? ~u : (u | 0x80000000u);
}
__device__ __forceinline__ float ord2f(unsigned int o) {
  unsigned int u = (o & 0x80000000u) ? (o ^ 0x80000000u) : ~o;
  return __uint_as_float(u);
}
// round-to-nearest-even fp32 -> bf16
__device__ __forceinline__ unsigned short bf16rne(float f, float* hif) {
  unsigned int u = __float_as_uint(f);
  unsigned int r = (u + 0x7fffu + ((u >> 16) & 1u)) >> 16;
  *hif = __uint_as_float(r << 16);
  return (unsigned short)r;
}
__device__ __forceinline__ void bf16split(float f, unsigned short* hi, unsigned short* lo) {
  float hif, d;
  *hi = bf16rne(f, &hif);
  *lo = bf16rne(f - hif, &d);
}

__device__ __forceinline__ void fma16(const float4 a, const float4 b, float acc[4][4]) {
  const float av[4] = {a.x, a.y, a.z, a.w};
  const float bv[4] = {b.x, b.y, b.z, b.w};
#pragma unroll
  for (int ii = 0; ii < 4; ++ii)
#pragma unroll
    for (int jj = 0; jj < 4; ++jj)
      acc[ii][jj] = fmaf(av[ii], bv[jj], acc[ii][jj]);
}

// ---------------- K0a: wnorm[c] = ||emb[c]||^2 ----------------
__global__ __launch_bounds__(256)
void wnorm_kernel(const float* __restrict__ emb, float* __restrict__ wnorm) {
  const int lane = threadIdx.x & 63, wv = threadIdx.x >> 6;
  const int c = blockIdx.x * 4 + wv;
  const float4 v = *(const float4*)(emb + (long)c * L_ + (lane << 2));
  float s = v.x * v.x + v.y * v.y + v.z * v.z + v.w * v.w;
#pragma unroll
  for (int off = 32; off > 0; off >>= 1) s += __shfl_down(s, off, 64);
  if (lane == 0) wnorm[c] = s;
}

// ---------------- K0b: emb -> bf16 hi/lo ----------------
__global__ __launch_bounds__(256)
void cvt_emb_kernel(const float* __restrict__ emb, unsigned short* __restrict__ hi,
                    unsigned short* __restrict__ lo) {
  const size_t i = ((size_t)blockIdx.x * 256 + threadIdx.x) * 4;
  const float4 v = *(const float4*)(emb + i);
  ushort4 hv, lv;
  bf16split(v.x, &hv.x, &lv.x);
  bf16split(v.y, &hv.y, &lv.y);
  bf16split(v.z, &hv.z, &lv.z);
  bf16split(v.w, &hv.w, &lv.w);
  *(ushort4*)(hi + i) = hv;
  *(ushort4*)(lo + i) = lv;
}

// ---------------- K0c: transpose+split: dst[c][r] = src[r][c] (hi/lo bf16) ----------------
__global__ __launch_bounds__(256)
void tsplit_kernel(const float* __restrict__ src, int srows, int scols,
                   unsigned short* __restrict__ hi, unsigned short* __restrict__ lo) {
  __shared__ float tile[64][68];
  const int t = threadIdx.x;
  const int r0 = blockIdx.y * 64, c0 = blockIdx.x * 64;
  const int a = t & 63, q = t >> 6;
#pragma unroll
  for (int i = 0; i < 4; ++i) {
    const int cq = q * 16 + i * 4;
    *(float4*)&tile[a][cq] = *(const float4*)(src + (size_t)(r0 + a) * scols + c0 + cq);
  }
  __syncthreads();
  const int rx = t & 15, cy = t >> 4;
#pragma unroll
  for (int i = 0; i < 4; ++i) {
    const int cl = i * 16 + cy;
    float4 w;
    w.x = tile[rx * 4 + 0][cl];
    w.y = tile[rx * 4 + 1][cl];
    w.z = tile[rx * 4 + 2][cl];
    w.w = tile[rx * 4 + 3][cl];
    ushort4 hv, lv;
    bf16split(w.x, &hv.x, &lv.x);
    bf16split(w.y, &hv.y, &lv.y);
    bf16split(w.z, &hv.z, &lv.z);
    bf16split(w.w, &hv.w, &lv.w);
    *(ushort4*)(hi + (size_t)(c0 + cl) * srows + r0 + rx * 4) = hv;
    *(ushort4*)(lo + (size_t)(c0 + cl) * srows + r0 + rx * 4) = lv;
  }
}

// ---------------- K1: partial h chains: hp[by] = x[:, by-quarter] @ w1[by-quarter] ----
// grid (128, 4), 256 threads (4 waves). BM=128, BK=32, K-split x4 -> 512
// blocks = 2 blocks/CU = 8 waves/CU = 2 waves/SIMD. Two-factor model from
// R3/R6/R7: need FMA:ds ratio >= 10.7 (LDS-pipe bound) AND 2 waves/SIMD
// (latency hiding) SIMULTANEOUSLY. R6 had ratio w/o waves (54us), R7 had
// better ratio w/o waves (62us), R3 had waves w/o ratio (58us).
// Thread tile 8 rows x 4 cols: per k = 2 a-reads + 1 b-read per 32
// FMA-instr -> LDS bound 73K cyc/CU = 30.5us; FMA floor 13.7us.
// Raw partials; enc2 combines: h = relu(((hp0+hp1)+hp2)+hp3 + b1)
// (same reorder class as R6/R7 -- passed, absmax unchanged).
// Banks: a-reads broadcast x4 distinct 32B-spaced addrs (free), b-read
// 2-way+broadcast (free), transpose-writes 2-way (free).
__global__ __launch_bounds__(256)
void enc1_kernel(const float* __restrict__ x, const float* __restrict__ w1,
                 float* __restrict__ hp) {
  __shared__ float xs[2][32][128];  // [buf][k][row]  32 KB
  __shared__ float ws[2][32][64];   // [buf][k][col]  16 KB
  const int t = threadIdx.x;        // 0..255
  const int lane = t & 63, wv = t >> 6;
  const int tx = t & 15;            // col-group: cols tx*4..+4
  const int ty = t >> 4;            // row-group: rows ty*8..+8 (0..15)
  const long row0 = (long)blockIdx.x * 128;
  const int kbase = blockIdx.y * 256;
  const int srow = t >> 1;          // staging row 0..127
  const int kh = (t & 1) * 16;      // staging k-half-of-step

  float acc[8][4] = {};

#define ENC1_STAGE_W(buf, k0v)                                                     \
  do {                                                                             \
    const char* wsrc_ = (const char*)(w1 + (size_t)(k0v) * H_);                    \
    char* wdst_ = (char*)&ws[buf][0][0];                                           \
    _Pragma("unroll")                                                              \
    for (int is_ = 0; is_ < 2; ++is_)                                              \
      __builtin_amdgcn_global_load_lds(                                            \
          (const AS1 void*)(wsrc_ + (wv * 2 + is_) * 1024 + lane * 16),            \
          (AS3 void*)(wdst_ + (wv * 2 + is_) * 1024), 16, 0, 0);                   \
  } while (0)

  // prologue: stage step 0 (w via global_load_lds; x reg->transposed ds_write)
  ENC1_STAGE_W(0, kbase);
  {
    float4 cv[4];
#pragma unroll
    for (int j = 0; j < 4; ++j)
      cv[j] = *(const float4*)(x + (row0 + srow) * S_ + kbase + kh + 4 * j);
#pragma unroll
    for (int j = 0; j < 4; ++j)
#pragma unroll
      for (int jj = 0; jj < 4; ++jj)
        xs[0][kh + 4 * j + jj][srow] = ((const float*)&cv[j])[jj];
  }
  __syncthreads();

  for (int s = 0; s < 8; ++s) {
    const int cur = s & 1;
    float4 nv[4];
    const bool pf = (s < 7);
    if (pf) {
      const int k0n = kbase + (s + 1) * 32;
      ENC1_STAGE_W(cur ^ 1, k0n);
#pragma unroll
      for (int j = 0; j < 4; ++j)
        nv[j] = *(const float4*)(x + (row0 + srow) * S_ + k0n + kh + 4 * j);
    }
#pragma unroll 4
    for (int k = 0; k < 32; ++k) {
      const float4 a0 = *(const float4*)&xs[cur][k][ty * 8];
      const float4 a1 = *(const float4*)&xs[cur][k][ty * 8 + 4];
      const float4 b = *(const float4*)&ws[cur][k][tx * 4];
      const float av[8] = {a0.x, a0.y, a0.z, a0.w, a1.x, a1.y, a1.z, a1.w};
      const float bv[4] = {b.x, b.y, b.z, b.w};
#pragma unroll
      for (int ii = 0; ii < 8; ++ii)
#pragma unroll
        for (int jj = 0; jj < 4; ++jj)
          acc[ii][jj] = fmaf(av[ii], bv[jj], acc[ii][jj]);
    }
    if (pf) {
#pragma unroll
      for (int j = 0; j < 4; ++j)
#pragma unroll
        for (int jj = 0; jj < 4; ++jj)
          xs[cur ^ 1][kh + 4 * j + jj][srow] = ((const float*)&nv[j])[jj];
    }
    __syncthreads();
  }
#undef ENC1_STAGE_W

  float* hpo = hp + (size_t)blockIdx.y * B_ * H_;
#pragma unroll
  for (int ii = 0; ii < 8; ++ii) {
    float4 o;
    o.x = acc[ii][0];
    o.y = acc[ii][1];
    o.z = acc[ii][2];
    o.w = acc[ii][3];
    *(float4*)(hpo + (row0 + ty * 8 + ii) * H_ + tx * 4) = o;
  }
}

// ---------------- K2: e = h @ w2 + b2 (fp32 + bf16 hi/lo) ----------------
// grid (256, 2): column-split x2 -> 512 blocks = 2 blocks/CU. h combined
// during staging: h = relu(((hp0+hp1)+hp2)+hp3 + b1) (fixed order, bias
// last). hs [64][68] staged once per block; ws double-buffered via
// global_load_lds over this block's 2 column passes. 4x4 per thread.
__global__ __launch_bounds__(256)
void enc2_kernel(const float* __restrict__ hp, const float* __restrict__ w2,
                 const float* __restrict__ b1, const float* __restrict__ b2,
                 float* __restrict__ e32,
                 unsigned short* __restrict__ e_hi, unsigned short* __restrict__ e_lo) {
  __shared__ float hs[64][68];      // [k][row(+pad)]
  __shared__ float ws[2][64][64];   // [buf][k][col]
  const int t = threadIdx.x;
  const int lane = t & 63, wv = t >> 6;
  const int tx = t & 15, ty = t >> 4;
  const long row0 = (long)blockIdx.x * 64;
  const int p0 = blockIdx.y * 2;    // this block's 2 column passes

#define ENC2_STAGE_W(buf, c0v)                                                     \
  do {                                                                             \
    char* wdst_ = (char*)&ws[buf][0][0];                                           \
    _Pragma("unroll")                                                              \
    for (int is_ = 0; is_ < 4; ++is_) {                                            \
      const int krow_ = wv * 16 + is_ * 4 + (lane >> 4);                           \
      const float* src_ = w2 + (size_t)krow_ * L_ + (c0v) + (lane & 15) * 4;       \
      __builtin_amdgcn_global_load_lds((const AS1 void*)src_,                      \
          (AS3 void*)(wdst_ + (wv * 16 + is_ * 4) * 256), 16, 0, 0);               \
    }                                                                              \
  } while (0)

  // prologue: stage h tile (combine 4 partials + bias + relu, transposed)
  ENC2_STAGE_W(0, p0 * 64);
  {
    const int srow = t >> 2;
    const int kq4 = (t & 3) * 16;
    const float* h0 = hp;
    const float* h1 = hp + (size_t)B_ * H_;
    const float* h2 = hp + (size_t)2 * B_ * H_;
    const float* h3 = hp + (size_t)3 * B_ * H_;
    float4 cv[4];
#pragma unroll
    for (int j = 0; j < 4; ++j) {
      const size_t off = (size_t)(row0 + srow) * H_ + kq4 + 4 * j;
      const float4 va = *(const float4*)(h0 + off);
      const float4 vb = *(const float4*)(h1 + off);
      const float4 vc = *(const float4*)(h2 + off);
      const float4 vd = *(const float4*)(h3 + off);
      const float4 bb = *(const float4*)(b1 + kq4 + 4 * j);
      cv[j].x = fmaxf(((va.x + vb.x) + vc.x) + vd.x + bb.x, 0.f);
      cv[j].y = fmaxf(((va.y + vb.y) + vc.y) + vd.y + bb.y, 0.f);
      cv[j].z = fmaxf(((va.z + vb.z) + vc.z) + vd.z + bb.z, 0.f);
      cv[j].w = fmaxf(((va.w + vb.w) + vc.w) + vd.w + bb.w, 0.f);
    }
#pragma unroll
    for (int j = 0; j < 4; ++j)
#pragma unroll
      for (int jj = 0; jj < 4; ++jj)
        hs[kq4 + 4 * j + jj][srow] = ((const float*)&cv[j])[jj];
  }
  __syncthreads();

  for (int pi = 0; pi < 2; ++pi) {
    const int cur = pi & 1;
    const int c0 = (p0 + pi) * 64;
    if (pi < 1) ENC2_STAGE_W(cur ^ 1, c0 + 64);
    float acc[4][4] = {};
#pragma unroll 8
    for (int k = 0; k < 64; ++k) {
      const float4 a = *(const float4*)&hs[k][ty * 4];
      const float4 b = *(const float4*)&ws[cur][k][tx * 4];
      fma16(a, b, acc);
    }
    const float4 bb = *(const float4*)(b2 + c0 + tx * 4);
#pragma unroll
    for (int ii = 0; ii < 4; ++ii) {
      const long row = row0 + ty * 4 + ii;
      float4 o;
      o.x = acc[ii][0] + bb.x;
      o.y = acc[ii][1] + bb.y;
      o.z = acc[ii][2] + bb.z;
      o.w = acc[ii][3] + bb.w;
      *(float4*)(e32 + row * L_ + c0 + tx * 4) = o;
      ushort4 hv, lv;
      bf16split(o.x, &hv.x, &lv.x);
      bf16split(o.y, &hv.y, &lv.y);
      bf16split(o.z, &hv.z, &lv.z);
      bf16split(o.w, &hv.w, &lv.w);
      *(ushort4*)(e_hi + row * L_ + c0 + tx * 4) = hv;
      *(ushort4*)(e_lo + row * L_ + c0 + tx * 4) = lv;
    }
    __syncthreads();
  }
#undef ENC2_STAGE_W
}

// ---------------- K3: pass-1 hi*hi distance + per-row top-2 ----------------
// grid (B_/128, 8). 128 rows x 512 codes per block. Double-buffered staging,
// one barrier per step. 32-bit biased-score keys, branchless top-2.
// launch_bounds (256,3): cap ~170 VGPR+AGPR -> no spill (R1's (256,4) cap=128
// spilled acc -> 59 MB scratch writes/dispatch).
__global__ __launch_bounds__(256, 3)
void dist_hi_kernel(const unsigned short* __restrict__ emb_hi,
                    const unsigned short* __restrict__ e_hi,
                    const float* __restrict__ wnorm, uint4* __restrict__ part) {
  __shared__ char smem[32768];        // [buf][sA 8K | sB 8K]
  __shared__ float wnormb_s[512];
  const int t = threadIdx.x;
  const int lane = t & 63, wv = t >> 6;
  const int wm = wv >> 1, wn = wv & 1;
  const int n0 = blockIdx.x * 128;
  const int cbase = blockIdx.y * 512;

  const int lr = lane >> 2;
  const int sst = (lr + (lane >> 4)) & 3;
  const int qsrc = ((lane & 3) - sst) & 3;
  const size_t lane_goff = (size_t)lr * (L_ * 2) + (size_t)qsrc * 16;

  const int ln = lane & 15, quad = lane >> 4;
  const int sfr = (ln + (ln >> 2)) & 3;
  const int qp = (quad + sfr) & 3;

  const bool isA = (wv < 2);
  const size_t rowHalfOff = (size_t)((wv & 1) * 64) * (L_ * 2);
  const char* gA = (const char*)emb_hi + (size_t)cbase * (L_ * 2) + rowHalfOff + lane_goff;
  const char* gB = (const char*)e_hi + (size_t)n0 * (L_ * 2) + rowHalfOff + lane_goff;
  char* const dstBase = smem + (isA ? 0 : 8192) + (wv & 1) * 4096;

  // prologue: stage (mt=0,kc=0) into buf0; preload biased wnorm
  {
    const char* src = isA ? gA : gB;
#pragma unroll
    for (int is = 0; is < 4; ++is)
      __builtin_amdgcn_global_load_lds((const AS1 void*)(src + (size_t)is * (16 * L_ * 2)),
                                       (AS3 void*)(dstBase + is * 1024), 16, 0, 0);
  }
  wnormb_s[t] = wnorm[cbase + t] + SBIAS;
  wnormb_s[t + 256] = wnorm[cbase + t + 256] + SBIAS;

  unsigned int k1[4], i1[4], k2[4];
#pragma unroll
  for (int nf = 0; nf < 4; ++nf) { k1[nf] = 0xffffffffu; k2[nf] = 0xffffffffu; i1[nf] = 0u; }

  floatx4 acc[4][4];
#pragma unroll
  for (int a = 0; a < 4; ++a)
#pragma unroll
    for (int b = 0; b < 4; ++b) acc[a][b] = (floatx4){0.f, 0.f, 0.f, 0.f};

  __syncthreads();  // buf0 staged (vmcnt drained by compiler), wnormb_s ready

  for (int mt = 0; mt < 4; ++mt) {
#pragma unroll
    for (int kc = 0; kc < 8; ++kc) {
      // prefetch step s+1 into the other buffer (skip only at very last step)
      if (mt < 3 || kc < 7) {
        const int nmt = (kc == 7) ? mt + 1 : mt;
        const int nkc = (kc + 1) & 7;
        char* dst = dstBase + ((kc + 1) & 1) * 16384;
        const char* src = isA ? (gA + (size_t)nmt * (128 * L_ * 2) + nkc * 64)
                              : (gB + nkc * 64);
#pragma unroll
        for (int is = 0; is < 4; ++is)
          __builtin_amdgcn_global_load_lds((const AS1 void*)(src + (size_t)is * (16 * L_ * 2)),
                                           (AS3 void*)(dst + is * 1024), 16, 0, 0);
      }
      const char* sAc = smem + (kc & 1) * 16384;
      const char* sBc = sAc + 8192;
      short8 ahi[4];
#pragma unroll
      for (int mf = 0; mf < 4; ++mf)
        ahi[mf] = *(const short8*)(sAc + (wm * 64 + mf * 16 + ln) * 64 + qp * 16);
#pragma unroll
      for (int nf = 0; nf < 4; ++nf) {
        const short8 bh = *(const short8*)(sBc + (wn * 64 + nf * 16 + ln) * 64 + qp * 16);
#pragma unroll
        for (int mf = 0; mf < 4; ++mf)
          acc[mf][nf] = __builtin_amdgcn_mfma_f32_16x16x32_bf16(ahi[mf], bh, acc[mf][nf], 0, 0, 0);
      }
      if (kc == 7) {
        // epilogue for this mt tile (overlaps with next tile's staging)
        const int mb = mt * 128 + wm * 64 + quad * 4;
        const unsigned int gb = (unsigned int)(cbase + mb);
#pragma unroll
        for (int mf = 0; mf < 4; ++mf) {
          const float4 w4 = *(const float4*)&wnormb_s[mb + mf * 16];
          const float* wp = (const float*)&w4;
#pragma unroll
          for (int nf = 0; nf < 4; ++nf) {
#pragma unroll
            for (int rr = 0; rr < 4; ++rr) {
              const float score = fmaf(-2.f, acc[mf][nf][rr], wp[rr]);
              const unsigned int k = __float_as_uint(score);
              const unsigned int id = gb + (unsigned int)(mf * 16 + rr);
              const bool lt1 = k < k1[nf];
              const bool lt2 = k < k2[nf];
              k2[nf] = lt1 ? k1[nf] : (lt2 ? k : k2[nf]);
              k1[nf] = lt1 ? k : k1[nf];
              i1[nf] = lt1 ? id : i1[nf];
              acc[mf][nf][rr] = 0.f;
            }
          }
        }
      }
      __syncthreads();
    }
  }
  // reduce across quads (lane bits 4,5)
#pragma unroll
  for (int d = 16; d <= 32; d <<= 1) {
#pragma unroll
    for (int nf = 0; nf < 4; ++nf) {
      const unsigned int ok1 = __shfl_xor(k1[nf], d, 64);
      const unsigned int oi1 = __shfl_xor(i1[nf], d, 64);
      const unsigned int ok2 = __shfl_xor(k2[nf], d, 64);
      const bool c = ok1 < k1[nf];
      const unsigned int hk = c ? k1[nf] : ok1;
      k1[nf] = c ? ok1 : k1[nf];
      i1[nf] = c ? oi1 : i1[nf];
      const unsigned int mk = ok2 < k2[nf] ? ok2 : k2[nf];
      k2[nf] = hk < mk ? hk : mk;
    }
  }
  if (lane < 16) {
    const int slice = blockIdx.y * 2 + wm;
#pragma unroll
    for (int nf = 0; nf < 4; ++nf) {
      const int row = n0 + wn * 64 + nf * 16 + lane;
      uint4 v;
      v.x = k1[nf]; v.y = i1[nf]; v.z = k2[nf]; v.w = 0u;
      part[(size_t)slice * B_ + row] = v;
    }
  }
}

// ---------------- K4: merge pass-1 partials, flag coarse-gap rows ----------------
__global__ __launch_bounds__(256)
void finalize1_kernel(const uint4* __restrict__ part, int* __restrict__ idx,
                      int* __restrict__ flagged, int* __restrict__ counter) {
  const int row = blockIdx.x * 256 + threadIdx.x;
  unsigned int k1 = 0xffffffffu, i1 = 0u, k2 = 0xffffffffu;
#pragma unroll
  for (int s = 0; s < 16; ++s) {
    const uint4 v = part[(size_t)s * B_ + row];
    const bool c = v.x < k1;
    const unsigned int hk = c ? k1 : v.x;
    k1 = c ? v.x : k1;
    i1 = c ? v.y : i1;
    const unsigned int mk = v.z < k2 ? v.z : k2;
    k2 = hk < mk ? hk : mk;
  }
  idx[row] = (int)i1;
  const float gap = __uint_as_float(k2) - __uint_as_float(k1);
  if (gap < TAU1) {
    const int p = atomicAdd(counter, 1);
    flagged[p] = row;
  }
}

// ---------------- K5: pass-2 3-term split-bf16 on flagged rows ----------------
// grid (16 rowgroup-stride, 16 slices of 256 codes); gathered e rows.
// Same pipeline treatment as dist_hi: double-buffered LDS (2x32K), flattened
// (mt,kc) steps with prefetch-before-compute, one barrier/step, 32-bit keys.
__global__ __launch_bounds__(256)
void dist3_kernel(const unsigned short* __restrict__ emb_hi, const unsigned short* __restrict__ emb_lo,
                  const unsigned short* __restrict__ e_hi, const unsigned short* __restrict__ e_lo,
                  const float* __restrict__ wnorm, const int* __restrict__ counter,
                  const int* __restrict__ flagged, uint4* __restrict__ part2) {
  __shared__ char smem[2][4 * 8192];   // [buf][Ahi|Alo|Bhi|Blo]
  __shared__ float wnormb_s[256];
  __shared__ int frow_s[128];
  const int t = threadIdx.x;
  const int lane = t & 63, wv = t >> 6;
  const int wm = wv >> 1, wn = wv & 1;
  const int slice = blockIdx.y;
  const int n = min(*counter, SLOTCAP);

  const int lr = lane >> 2;
  const int sst = (lr + (lane >> 4)) & 3;
  const int qsrc = ((lane & 3) - sst) & 3;
  const int ln = lane & 15, quad = lane >> 4;
  const int sfr = (ln + (ln >> 2)) & 3;
  const int qp = (quad + sfr) & 3;

  const bool isA = (wv < 2);
  const unsigned short* aBase = (wv & 1) ? emb_lo : emb_hi;
  const unsigned short* bBase = (wv & 1) ? e_lo : e_hi;

  wnormb_s[t] = wnorm[slice * 256 + t] + SBIAS;

  floatx4 acc[4][4];
#pragma unroll
  for (int a = 0; a < 4; ++a)
#pragma unroll
    for (int b = 0; b < 4; ++b) acc[a][b] = (floatx4){0.f, 0.f, 0.f, 0.f};

#define STAGE3(bufidx, m0v, kcv)                                                        \
  do {                                                                                  \
    char* dst_ = smem[bufidx] + wv * 8192;                                              \
    _Pragma("unroll")                                                                   \
    for (int is_ = 0; is_ < 8; ++is_) {                                                 \
      const int row_ = is_ * 16 + lr;                                                   \
      const char* src_ = isA ? (const char*)(aBase + (size_t)((m0v) + row_) * L_)       \
                             : (const char*)(bBase + (size_t)frow_s[row_] * L_);        \
      src_ += (kcv) * 64 + qsrc * 16;                                                   \
      __builtin_amdgcn_global_load_lds((const AS1 void*)src_,                           \
                                       (AS3 void*)(dst_ + is_ * 1024), 16, 0, 0);       \
    }                                                                                   \
  } while (0)

  for (int gi = blockIdx.x; gi * 128 < n; gi += 16) {
    const int s0 = gi * 128;
    __syncthreads();                       // prev gi fully done with LDS
    if (t < 128) frow_s[t] = flagged[min(s0 + t, n - 1)];
    __syncthreads();                       // frow_s ready (and wnormb_s on first gi)
    STAGE3(0, slice * 256, 0);             // stage step 0 (mt=0, kc=0)

    unsigned int k1[4], i1[4], k2[4];
#pragma unroll
    for (int nf = 0; nf < 4; ++nf) { k1[nf] = 0xffffffffu; k2[nf] = 0xffffffffu; i1[nf] = 0u; }

    __syncthreads();                       // buf0 staged (vmcnt drained)

    for (int s = 0; s < 16; ++s) {
      const int mt = s >> 3, kc = s & 7;
      if (s < 15) {
        const int ns = s + 1;
        STAGE3(ns & 1, slice * 256 + (ns >> 3) * 128, ns & 7);
      }
      const char* base = smem[s & 1];
      const char* sAhi = base;
      const char* sAlo = base + 8192;
      const char* sBhi = base + 16384;
      const char* sBlo = base + 24576;
      short8 ahi[4], alo[4];
#pragma unroll
      for (int mf = 0; mf < 4; ++mf) {
        const int rb = (mf * 16 + wm * 64 + ln) * 64 + qp * 16;
        ahi[mf] = *(const short8*)(sAhi + rb);
        alo[mf] = *(const short8*)(sAlo + rb);
      }
#pragma unroll
      for (int nf = 0; nf < 4; ++nf) {
        const int rb = (nf * 16 + wn * 64 + ln) * 64 + qp * 16;
        const short8 bhi = *(const short8*)(sBhi + rb);
        const short8 blo = *(const short8*)(sBlo + rb);
#pragma unroll
        for (int mf = 0; mf < 4; ++mf) {
          acc[mf][nf] = __builtin_amdgcn_mfma_f32_16x16x32_bf16(ahi[mf], bhi, acc[mf][nf], 0, 0, 0);
          acc[mf][nf] = __builtin_amdgcn_mfma_f32_16x16x32_bf16(ahi[mf], blo, acc[mf][nf], 0, 0, 0);
          acc[mf][nf] = __builtin_amdgcn_mfma_f32_16x16x32_bf16(alo[mf], bhi, acc[mf][nf], 0, 0, 0);
        }
      }
      if (kc == 7) {
        const int mb = mt * 128 + wm * 64 + quad * 4;
        const unsigned int gb = (unsigned int)(slice * 256 + mb);
#pragma unroll
        for (int mf = 0; mf < 4; ++mf) {
          const float4 w4 = *(const float4*)&wnormb_s[mb + mf * 16];
          const float* wp = (const float*)&w4;
#pragma unroll
          for (int nf = 0; nf < 4; ++nf) {
#pragma unroll
            for (int rr = 0; rr < 4; ++rr) {
              const float score = fmaf(-2.f, acc[mf][nf][rr], wp[rr]);
              const unsigned int k = __float_as_uint(score);
              const unsigned int id = gb + (unsigned int)(mf * 16 + rr);
              const bool lt1 = k < k1[nf];
              const bool lt2 = k < k2[nf];
              k2[nf] = lt1 ? k1[nf] : (lt2 ? k : k2[nf]);
              k1[nf] = lt1 ? k : k1[nf];
              i1[nf] = lt1 ? id : i1[nf];
              acc[mf][nf][rr] = 0.f;
            }
          }
        }
      }
      __syncthreads();
    }
    // reduce across quads (lane bits 4,5)
#pragma unroll
    for (int d = 16; d <= 32; d <<= 1) {
#pragma unroll
      for (int nf = 0; nf < 4; ++nf) {
        const unsigned int ok1 = __shfl_xor(k1[nf], d, 64);
        const unsigned int oi1 = __shfl_xor(i1[nf], d, 64);
        const unsigned int ok2 = __shfl_xor(k2[nf], d, 64);
        const bool c = ok1 < k1[nf];
        const unsigned int hk = c ? k1[nf] : ok1;
        k1[nf] = c ? ok1 : k1[nf];
        i1[nf] = c ? oi1 : i1[nf];
        const unsigned int mk = ok2 < k2[nf] ? ok2 : k2[nf];
        k2[nf] = hk < mk ? hk : mk;
      }
    }
    if (lane < 16) {
      const int sub = slice * 2 + wm;   // 32 sub-slices
#pragma unroll
      for (int nf = 0; nf < 4; ++nf) {
        const int slot = s0 + wn * 64 + nf * 16 + lane;
        if (slot < n) {
          uint4 v;
          v.x = k1[nf]; v.y = i1[nf]; v.z = k2[nf]; v.w = 0u;
          part2[(size_t)sub * SLOTCAP + slot] = v;
        }
      }
    }
  }
#undef STAGE3
}

// ---------------- K6: merge pass-2 partials, flag fine-gap rows ----------------
__global__ __launch_bounds__(256)
void finalize2_kernel(const uint4* __restrict__ part2, const int* __restrict__ counter,
                      const int* __restrict__ flagged, int* __restrict__ idx,
                      int* __restrict__ flagged2, int* __restrict__ counter2) {
  const int n = min(*counter, SLOTCAP);
  const int s = blockIdx.x * 256 + threadIdx.x;
  if (s >= n) return;
  unsigned int k1 = 0xffffffffu, i1 = 0u, k2 = 0xffffffffu;
#pragma unroll
  for (int sub = 0; sub < 32; ++sub) {
    const uint4 v = part2[(size_t)sub * SLOTCAP + s];
    const bool c = v.x < k1;
    const unsigned int hk = c ? k1 : v.x;
    k1 = c ? v.x : k1;
    i1 = c ? v.y : i1;
    const unsigned int mk = v.z < k2 ? v.z : k2;
    k2 = hk < mk ? hk : mk;
  }
  const int row = flagged[s];
  idx[row] = (int)i1;
  if (__uint_as_float(k2) - __uint_as_float(k1) < TAU2) {
    const int p = atomicAdd(counter2, 1);
    flagged2[p] = row;
  }
}

// ---------------- K7: exact fp32 recheck (parallel over code chunks) ----------------
// grid (16 code-chunks, 16 row-slots)
__global__ __launch_bounds__(256)
void recheck_kernel(const int* __restrict__ counter2, const int* __restrict__ flagged2,
                    const float* __restrict__ e32, const float* __restrict__ emb,
                    const float* __restrict__ wnorm, unsigned long long* __restrict__ keys2) {
  __shared__ float er[L_];
  const int t = threadIdx.x;
  const int lane = t & 63;
  const int n2 = *counter2;
  for (int i = blockIdx.y; i < n2; i += 16) {
    const int row = flagged2[i];
    __syncthreads();
    er[t] = e32[(size_t)row * L_ + t];
    __syncthreads();
    const int c = blockIdx.x * 256 + t;
    const float4* wr = (const float4*)(emb + (size_t)c * L_);
    float dot = 0.f;
#pragma unroll 16
    for (int l = 0; l < 64; ++l) {
      const float4 w = wr[l];
      dot = fmaf(w.x, er[4 * l + 0], dot);
      dot = fmaf(w.y, er[4 * l + 1], dot);
      dot = fmaf(w.z, er[4 * l + 2], dot);
      dot = fmaf(w.w, er[4 * l + 3], dot);
    }
    const float score = fmaf(-2.f, dot, wnorm[c]);
    unsigned long long key = ((unsigned long long)f2ord(score) << 32) | (unsigned int)c;
#pragma unroll
    for (int off = 32; off > 0; off >>= 1) {
      const unsigned long long o = __shfl_down(key, off, 64);
      key = o < key ? o : key;
    }
    if (lane == 0) atomicMin(&keys2[row], key);
  }
}

// ---------------- K8: write rechecked indices ----------------
__global__ __launch_bounds__(256)
void extract_kernel(const int* __restrict__ counter2, const int* __restrict__ flagged2,
                    const unsigned long long* __restrict__ keys2, int* __restrict__ idx) {
  const int n2 = *counter2;
  for (int i = threadIdx.x; i < n2; i += 256) {
    const int r = flagged2[i];
    idx[r] = (int)(keys2[r] & 0xffffffffull);
  }
}

// ---------------- K9: decoder, split-bf16 MFMA ----------------
// grid (B_/64, 2): blockIdx.y splits the output-S range (nc 0..3 vs 4..7).
__global__ __launch_bounds__(256)
void dec_mfma_kernel(const int* __restrict__ idx,
                     const unsigned short* __restrict__ emb_hi, const unsigned short* __restrict__ emb_lo,
                     const unsigned short* __restrict__ w1t_hi, const unsigned short* __restrict__ w1t_lo,
                     const unsigned short* __restrict__ w2t_hi, const unsigned short* __restrict__ w2t_lo,
                     const float* __restrict__ b1, const float* __restrict__ b2,
                     float* __restrict__ out) {
  __shared__ char stage[32768];
  __shared__ __align__(16) unsigned short g_hi[64][72];
  __shared__ __align__(16) unsigned short g_lo[64][72];
  __shared__ int idxs[64];
  const int t = threadIdx.x;
  const int lane = t & 63, wv = t >> 6;
  const long row0 = (long)blockIdx.x * 64;
  const int nc0 = blockIdx.y * 4;

  const int lr = lane >> 2;
  const int sst = (lr + (lane >> 4)) & 3;
  const int qsrc = ((lane & 3) - sst) & 3;
  const int ln = lane & 15, quad = lane >> 4;
  const int sfr = (ln + (ln >> 2)) & 3;
  const int qp = (quad + sfr) & 3;

  if (t < 64) idxs[t] = idx[row0 + t];
  __syncthreads();

  floatx4 acc1[4];
#pragma unroll
  for (int nf = 0; nf < 4; ++nf) acc1[nf] = (floatx4){0.f, 0.f, 0.f, 0.f};

  for (int kc = 0; kc < 8; ++kc) {
    char* dst = stage + wv * 4096;
#pragma unroll
    for (int is = 0; is < 4; ++is) {
      const int row = is * 16 + lr;
      const char* src;
      if (wv == 0)      src = (const char*)(emb_hi + (size_t)idxs[row] * L_) + kc * 64 + qsrc * 16;
      else if (wv == 1) src = (const char*)(emb_lo + (size_t)idxs[row] * L_) + kc * 64 + qsrc * 16;
      else if (wv == 2) src = (const char*)(w1t_hi + (size_t)row * L_) + kc * 64 + qsrc * 16;
      else              src = (const char*)(w1t_lo + (size_t)row * L_) + kc * 64 + qsrc * 16;
      __builtin_amdgcn_global_load_lds((const AS1 void*)src, (AS3 void*)(dst + is * 1024), 16, 0, 0);
    }
    __syncthreads();
    const int arb = (16 * wv + ln) * 64 + qp * 16;
    const short8 ahi = *(const short8*)(stage + arb);
    const short8 alo = *(const short8*)(stage + 4096 + arb);
#pragma unroll
    for (int nf = 0; nf < 4; ++nf) {
      const int brb = (nf * 16 + ln) * 64 + qp * 16;
      const short8 bhi = *(const short8*)(stage + 8192 + brb);
      const short8 blo = *(const short8*)(stage + 12288 + brb);
      acc1[nf] = __builtin_amdgcn_mfma_f32_16x16x32_bf16(ahi, bhi, acc1[nf], 0, 0, 0);
      acc1[nf] = __builtin_amdgcn_mfma_f32_16x16x32_bf16(ahi, blo, acc1[nf], 0, 0, 0);
      acc1[nf] = __builtin_amdgcn_mfma_f32_16x16x32_bf16(alo, bhi, acc1[nf], 0, 0, 0);
    }
    __syncthreads();
  }
#pragma unroll
  for (int nf = 0; nf < 4; ++nf) {
    const int col = nf * 16 + ln;
    const float bias = b1[col];
#pragma unroll
    for (int rr = 0; rr < 4; ++rr) {
      const int row = 16 * wv + quad * 4 + rr;
      const float gv = fmaxf(acc1[nf][rr] + bias, 0.f);
      unsigned short hv, lv;
      bf16split(gv, &hv, &lv);
      g_hi[row][col] = hv;
      g_lo[row][col] = lv;
    }
  }
  __syncthreads();

  for (int nc = nc0; nc < nc0 + 4; ++nc) {
    char* dst = stage + wv * 8192;
    const unsigned short* base = (wv < 2) ? w2t_hi : w2t_lo;
    const int kh = wv & 1;
#pragma unroll
    for (int is = 0; is < 8; ++is) {
      const int row = is * 16 + lr;
      const char* src = (const char*)(base + (size_t)(nc * 128 + row) * H_) + kh * 64 + qsrc * 16;
      __builtin_amdgcn_global_load_lds((const AS1 void*)src, (AS3 void*)(dst + is * 1024), 16, 0, 0);
    }
    __syncthreads();
    floatx4 acc2[8];
#pragma unroll
    for (int nf = 0; nf < 8; ++nf) acc2[nf] = (floatx4){0.f, 0.f, 0.f, 0.f};
#pragma unroll
    for (int ks = 0; ks < 2; ++ks) {
      const int ab = (16 * wv + ln) * 144 + ks * 64 + quad * 16;
      const short8 ahi = *(const short8*)((const char*)g_hi + ab);
      const short8 alo = *(const short8*)((const char*)g_lo + ab);
#pragma unroll
      for (int nf = 0; nf < 8; ++nf) {
        const int brb = (nf * 16 + ln) * 64 + qp * 16;
        const short8 bhi = *(const short8*)(stage + ks * 8192 + brb);
        const short8 blo = *(const short8*)(stage + (2 + ks) * 8192 + brb);
        acc2[nf] = __builtin_amdgcn_mfma_f32_16x16x32_bf16(ahi, bhi, acc2[nf], 0, 0, 0);
        acc2[nf] = __builtin_amdgcn_mfma_f32_16x16x32_bf16(ahi, blo, acc2[nf], 0, 0, 0);
        acc2[nf] = __builtin_amdgcn_mfma_f32_16x16x32_bf16(alo, bhi, acc2[nf], 0, 0, 0);
      }
    }
    __syncthreads();
#pragma unroll
    for (int nf = 0; nf < 8; ++nf) {
      const int s = nc * 128 + nf * 16 + ln;
      const float bias = b2[s];
#pragma unroll
      for (int rr = 0; rr < 4; ++rr) {
        const long row = row0 + 16 * wv + quad * 4 + rr;
        out[row * S_ + s] = acc2[nf][rr] + bias;
      }
    }
  }
}

extern "C" void kernel_launch(void* const* d_in, const int* in_sizes, int n_in,
                              void* d_out, int out_size, void* d_ws, size_t ws_size,
                              hipStream_t stream) {
  (void)in_sizes; (void)n_in; (void)out_size; (void)ws_size;
  const float* x      = (const float*)d_in[0];
  const float* enc_w1 = (const float*)d_in[1];
  const float* enc_b1 = (const float*)d_in[2];
  const float* enc_w2 = (const float*)d_in[3];
  const float* enc_b2 = (const float*)d_in[4];
  const float* emb    = (const float*)d_in[5];
  const float* dec_w1 = (const float*)d_in[6];
  const float* dec_b1 = (const float*)d_in[7];
  const float* dec_w2 = (const float*)d_in[8];
  const float* dec_b2 = (const float*)d_in[9];
  float* out = (float*)d_out;

  char* p = (char*)d_ws;
  float* hp   = (float*)p;          p += (size_t)4 * B_ * H_ * 4; // 16 MB (4 k-quarters)
  // hp is dead after enc2; part/part2 alias into it (stream order serializes)
  uint4* part  = (uint4*)hp;                                      // 4 MB (dist_hi)
  uint4* part2 = (uint4*)((char*)hp + (size_t)16 * B_ * 16);      // 4 MB (dist3)
  float* e32  = (float*)p;          p += (size_t)B_ * L_ * 4;   // 16 MB
  unsigned short* e_hi = (unsigned short*)p;   p += (size_t)B_ * L_ * 2;  // 8 MB
  unsigned short* e_lo = (unsigned short*)p;   p += (size_t)B_ * L_ * 2;  // 8 MB
  unsigned short* emb_hi = (unsigned short*)p; p += (size_t)K_ * L_ * 2;  // 2 MB
  unsigned short* emb_lo = (unsigned short*)p; p += (size_t)K_ * L_ * 2;  // 2 MB
  unsigned short* w1t_hi = (unsigned short*)p; p += (size_t)H_ * L_ * 2;  // 32 KB
  unsigned short* w1t_lo = (unsigned short*)p; p += (size_t)H_ * L_ * 2;  // 32 KB
  unsigned short* w2t_hi = (unsigned short*)p; p += (size_t)S_ * H_ * 2;  // 128 KB
  unsigned short* w2t_lo = (unsigned short*)p; p += (size_t)S_ * H_ * 2;  // 128 KB
  float* wnrm = (float*)p;          p += (size_t)K_ * 4;        // 16 KB
  unsigned long long* keys2 = (unsigned long long*)p; p += (size_t)B_ * 8; // 128 KB
  int* idx      = (int*)p;          p += (size_t)B_ * 4;        // 64 KB
  int* flagged  = (int*)p;          p += (size_t)B_ * 4;        // 64 KB
  int* flagged2 = (int*)p;          p += (size_t)B_ * 4;        // 64 KB
  int* counters = (int*)p;          p += 256;                   // [0]=n flagged, [1]=n2

  hipMemsetAsync(counters, 0, 8, stream);
  hipMemsetAsync(keys2, 0xFF, (size_t)B_ * 8, stream);
  wnorm_kernel<<<K_ / 4, 256, 0, stream>>>(emb, wnrm);
  cvt_emb_kernel<<<(K_ * L_) / 1024, 256, 0, stream>>>(emb, emb_hi, emb_lo);
  tsplit_kernel<<<dim3(1, 4), 256, 0, stream>>>(dec_w1, L_, H_, w1t_hi, w1t_lo);
  tsplit_kernel<<<dim3(16, 1), 256, 0, stream>>>(dec_w2, H_, S_, w2t_hi, w2t_lo);
  enc1_kernel<<<dim3(B_ / 128, 4), 256, 0, stream>>>(x, enc_w1, hp);
  enc2_kernel<<<dim3(B_ / 64, 2), 256, 0, stream>>>(hp, enc_w2, enc_b1, enc_b2,
                                                    e32, e_hi, e_lo);
  dist_hi_kernel<<<dim3(B_ / 128, 8), 256, 0, stream>>>(emb_hi, e_hi, wnrm, part);
  finalize1_kernel<<<B_ / 256, 256, 0, stream>>>(part, idx, flagged, counters);
  dist3_kernel<<<dim3(16, 16), 256, 0, stream>>>(emb_hi, emb_lo, e_hi, e_lo, wnrm,
                                                 counters, flagged, part2);
  finalize2_kernel<<<SLOTCAP / 256, 256, 0, stream>>>(part2, counters, flagged, idx,
                                                      flagged2, counters + 1);
  recheck_kernel<<<dim3(16, 16), 256, 0, stream>>>(counters + 1, flagged2, e32, emb, wnrm, keys2);
  extract_kernel<<<1, 256, 0, stream>>>(counters + 1, flagged2, keys2, idx);
  dec_mfma_kernel<<<dim3(B_ / 64, 2), 256, 0, stream>>>(idx, emb_hi, emb_lo, w1t_hi, w1t_lo,
                                                        w2t_hi, w2t_lo, dec_b1, dec_b2, out);
}